// Round 4
// baseline (244.538 us; speedup 1.0000x reference)
//
#include <hip/hip_runtime.h>
#include <stdint.h>
#include <math.h>

// Problem constants
constexpr int Kk  = 1024;

// d_out layout (floats)
constexpr int OUT0_N   = 32 * 64 * 1024;       // 2097152 (z_st, [B,D,H,W])
constexpr int OUT_LOSS = OUT0_N;               // 2097152
constexpr int OUT_PERP = OUT0_N + 1;           // 2097153
constexpr int OUT_ENC  = OUT0_N + 2;           // 2097154

// d_ws layout (bytes) — everything fully written each call (ws is poisoned):
//   [0      .. 4096)     counts u32[1024]      (zeroed by dist block 0)
//   [4096   .. 12288)    loss partials double[1024] (fully written by finish)
//   [12288  .. 12320)    maxbn float[8]        per-cg max code norm (rg0 blocks)
//   [16384  .. 2113536)  lockey u64[32768][8]  per-(row,cg): {local-min f32 hi,
//                        cnt+3x10bit candidate codes lo} — PLAIN stores, fully
//                        written by dist. No memsets, no contended atomics.
constexpr size_t WS_CNT = 0;
constexpr size_t WS_LP  = 4096;
constexpr size_t WS_MBN = 12288;
constexpr size_t WS_KEY = 16384;

typedef short bf16x8 __attribute__((ext_vector_type(8)));
typedef float f32x16 __attribute__((ext_vector_type(16)));

// ---------------------------------------------------------------------------
// numpy-bit-exact 64-elem squared-norm: tt[d]=fl(x*x), 8 stride-8 sequential
// accumulators, pairwise combine. Contraction OFF. p: 16B-aligned, contiguous.
// ---------------------------------------------------------------------------
__device__ __forceinline__ float norm64v(const float4* __restrict__ p) {
#pragma clang fp contract(off)
    float tt[64];
#pragma unroll
    for (int q = 0; q < 16; ++q) {
        float4 v = p[q];
        tt[4 * q + 0] = v.x * v.x;
        tt[4 * q + 1] = v.y * v.y;
        tt[4 * q + 2] = v.z * v.z;
        tt[4 * q + 3] = v.w * v.w;
    }
    float r[8];
#pragma unroll
    for (int j = 0; j < 8; ++j) r[j] = tt[j];
#pragma unroll
    for (int i = 8; i < 64; i += 8)
#pragma unroll
        for (int j = 0; j < 8; ++j) r[j] += tt[i + j];
    return ((r[0] + r[1]) + (r[2] + r[3])) + ((r[4] + r[5]) + (r[6] + r[7]));
}

__device__ __forceinline__ uint32_t fsort(float f) {
    uint32_t b = __float_as_uint(f);
    return (b & 0x80000000u) ? ~b : (b | 0x80000000u);
}

// RNE float->bf16 (finite inputs only; data is well inside normal range)
__device__ __forceinline__ unsigned short f2bf(float f) {
    uint32_t u = __float_as_uint(f);
    uint32_t r = (u + 0x7fffu + ((u >> 16) & 1u)) >> 16;
    return (unsigned short)r;
}

// exact distance key, bit-identical to the R5/R7 exact kernel:
// C = ascending-d sequential fma chain; A,B via norm64v; dist = fl(fl(A+B)-2C)
// (2C is exact, so fmaf(-2,C,s) == numpy's (A+B) - 2*C elementwise).
__device__ __forceinline__ unsigned long long
exact_key(float A, const float* __restrict__ xr, const float* __restrict__ emb,
          uint32_t code) {
    const float* er = emb + (size_t)code * 64;
    float C = 0.f;
#pragma unroll
    for (int d = 0; d < 64; ++d) C = __builtin_fmaf(xr[d], er[d], C);
    float Bv = norm64v((const float4*)er);
    float s = A + Bv;
    float dist = __builtin_fmaf(-2.f, C, s);
    return ((unsigned long long)fsort(dist) << 32) | code;
}

// ---------------------------------------------------------------------------
// dist_mfma: 2048 blocks = 256 rowgroups x 8 codegroups, 256 thr, ~34 KB LDS
// (bf16 tiles) -> 4 blocks/CU (R6 lesson: occupancy first). Screen math is
// R6's hardware-validated scheme: s_hat = Bn_exact - 2*(x.e)_bf16 via
// mfma_32x32x16_bf16; candidate set provably contains the numpy argmin:
//   |s_hat - (D-A)| <= 2^-8*1.01*2*||x||*||e|| (+tiny)  => margin = 2eps,
//   inflated: 0.017*sqrt(xsq*maxBn_local) + 1e-4   [R6-validated constants]
// Permutation-safety: A and B fragments packed with the SAME (lane>>5,elem)->d
// map, so the dot product is correct for ANY hardware k-order. C/D layout:
// col=lane&31, row=(r&3)+8*(r>>2)+4*(lane>>5)  [m74/m101, R6-validated].
// LDS tiles XOR-swizzled (byte ^= (row&7)<<4) to break the 128B-row-stride
// bank conflict (G4). Per-(row,cg) result: u64 {local_min, <=3 cands | OVF}.
// The 134 MB enc zero-fill is issued AFTER the last barrier, spread across
// the MFMA tiles — the kernel is store-drain-bound (~25us), compute hidden.
// ---------------------------------------------------------------------------
__global__ __launch_bounds__(256, 4)
void dist_mfma(const float* __restrict__ z_e, const float* __restrict__ emb,
               unsigned long long* __restrict__ lockey,
               uint32_t* __restrict__ counts,
               float* __restrict__ maxbn,
               float* __restrict__ out) {
    __shared__ unsigned short xbf[128 * 64];   // 16 KB bf16 rows, swizzled
    __shared__ unsigned short ebf[128 * 64];   // 16 KB bf16 codes, swizzled
    __shared__ float Bn_s[128];
    __shared__ float xsqp[2][128];
    __shared__ float mbn_s;
    const int t = threadIdx.x, lane = t & 63, wv = t >> 6, g = lane >> 5;
    const int rg = blockIdx.x >> 3, cg = blockIdx.x & 7;
    const int n0 = rg * 128, b = n0 >> 10, hw0 = n0 & 1023;
    const float* zb = z_e + (size_t)b * 65536 + hw0;

    // ---- x-tile: fp32 global (coalesced d-slices) -> bf16 LDS + xsq partials
    {
        int hwi = t & 127, d4g = t >> 7;
        float xq = 0.f;
#pragma unroll
        for (int it = 0; it < 8; ++it) {
            int dbase = (d4g + it * 2) * 4;
            float v0 = zb[(size_t)(dbase + 0) * 1024 + hwi];
            float v1 = zb[(size_t)(dbase + 1) * 1024 + hwi];
            float v2 = zb[(size_t)(dbase + 2) * 1024 + hwi];
            float v3 = zb[(size_t)(dbase + 3) * 1024 + hwi];
            xq = __builtin_fmaf(v0, v0, xq);
            xq = __builtin_fmaf(v1, v1, xq);
            xq = __builtin_fmaf(v2, v2, xq);
            xq = __builtin_fmaf(v3, v3, xq);
            ushort4 bv;
            bv.x = f2bf(v0); bv.y = f2bf(v1); bv.z = f2bf(v2); bv.w = f2bf(v3);
            *(ushort4*)((char*)xbf + hwi * 128 + ((dbase * 2) ^ ((hwi & 7) << 4))) = bv;
        }
        xsqp[d4g][hwi] = xq;
    }
    // ---- e-tile: contiguous 32 KB fp32 -> bf16 LDS (swizzled) ----
    {
        const float4* ep = (const float4*)(emb + (size_t)cg * 8192);
#pragma unroll
        for (int it = 0; it < 8; ++it) {
            int j = t + it * 256;            // 0..2047
            float4 v = ep[j];
            int code = j >> 4, q = j & 15;
            ushort4 bv;
            bv.x = f2bf(v.x); bv.y = f2bf(v.y); bv.z = f2bf(v.z); bv.w = f2bf(v.w);
            *(ushort4*)((char*)ebf + code * 128 + ((q * 8) ^ ((code & 7) << 4))) = bv;
        }
    }
    // exact code norms from global (L2-hot), numpy-bit-exact
    if (t < 128) Bn_s[t] = norm64v((const float4*)(emb + (size_t)(cg * 128 + t) * 64));
    if (blockIdx.x == 0) ((uint4*)counts)[t] = make_uint4(0u, 0u, 0u, 0u);
    __syncthreads();
    if (wv == 0) {
        float m = fmaxf(Bn_s[lane], Bn_s[lane + 64]);
#pragma unroll
        for (int s = 1; s < 64; s <<= 1) m = fmaxf(m, __shfl_xor(m, s, 64));
        if (lane == 0) { mbn_s = m; if (rg == 0) maxbn[cg] = m; }
    }
    __syncthreads();

    const int rowl = wv * 32 + (lane & 31);
    const float xsq = xsqp[0][rowl] + xsqp[1][rowl];
    const float margin = 0.017f * sqrtf(xsq * mbn_s) + 1.0e-4f;

    const int swz = (lane & 7) << 4;
    bf16x8 bfr[4];
    const char* xb = (const char*)xbf + rowl * 128;
#pragma unroll
    for (int s = 0; s < 4; ++s)
        bfr[s] = *(const bf16x8*)(xb + ((s * 32 + g * 16) ^ swz));
    const char* ebase = (const char*)ebf + (lane & 31) * 128;

    float4* encz = (float4*)(out + OUT_ENC) + (size_t)blockIdx.x * 4096;
    const float4 zero4 = make_float4(0.f, 0.f, 0.f, 0.f);

    // ---- pass 1: row min of s_hat (enc-fill stores ride along) ----
    float runmin = 3.4e38f;
#pragma unroll 1
    for (int tm = 0; tm < 4; ++tm) {
        encz[(size_t)(tm * 2 + 0) * 256 + t] = zero4;
        encz[(size_t)(tm * 2 + 1) * 256 + t] = zero4;
        const char* p = ebase + tm * 4096;
        f32x16 acc = {};
#pragma unroll
        for (int s = 0; s < 4; ++s)
            acc = __builtin_amdgcn_mfma_f32_32x32x16_bf16(
                *(const bf16x8*)(p + ((s * 32 + g * 16) ^ swz)), bfr[s], acc, 0, 0, 0);
#pragma unroll
        for (int r = 0; r < 16; ++r) {
            int cl = tm * 32 + (r & 3) + 8 * (r >> 2) + 4 * g;
            runmin = fminf(runmin, __builtin_fmaf(-2.f, acc[r], Bn_s[cl]));
        }
    }
    runmin = fminf(runmin, __shfl_xor(runmin, 32, 64));   // lane pair = same row
    const float thr = runmin + margin;

    // ---- pass 2: collect candidates (<=3/lane; MFMA recompute, cheap) ----
    uint32_t cnt = 0, c0 = 0, c1 = 0, c2 = 0;
#pragma unroll 1
    for (int tm = 0; tm < 4; ++tm) {
        encz[(size_t)(8 + tm * 2 + 0) * 256 + t] = zero4;
        encz[(size_t)(8 + tm * 2 + 1) * 256 + t] = zero4;
        const char* p = ebase + tm * 4096;
        f32x16 acc = {};
#pragma unroll
        for (int s = 0; s < 4; ++s)
            acc = __builtin_amdgcn_mfma_f32_32x32x16_bf16(
                *(const bf16x8*)(p + ((s * 32 + g * 16) ^ swz)), bfr[s], acc, 0, 0, 0);
#pragma unroll
        for (int r = 0; r < 16; ++r) {
            int cl = tm * 32 + (r & 3) + 8 * (r >> 2) + 4 * g;
            float sv = __builtin_fmaf(-2.f, acc[r], Bn_s[cl]);
            if (sv <= thr) {
                uint32_t gc = (uint32_t)(cg * 128 + cl);
                if (cnt == 0u) c0 = gc; else if (cnt == 1u) c1 = gc; else if (cnt == 2u) c2 = gc;
                ++cnt;
            }
        }
    }
    // merge with partner lane (lane^32: other code-subset of the same row)
    uint32_t pc = __shfl_xor(cnt, 32, 64);
    uint32_t p0 = __shfl_xor(c0, 32, 64);
    uint32_t p1 = __shfl_xor(c1, 32, 64);
    uint32_t p2 = __shfl_xor(c2, 32, 64);
    if (lane < 32) {
        uint32_t tot = cnt + pc;
        uint32_t lo;
        if (tot > 3u || tot == 0u) {
            lo = 3u << 30;                   // OVF -> finish scans this cg
        } else {
            uint32_t a0 = c0, a1 = c1, a2 = c2;
            if (cnt == 0u)      { a0 = p0; a1 = p1; a2 = p2; }
            else if (cnt == 1u) { a1 = p0; a2 = p1; }
            else if (cnt == 2u) { a2 = p0; }
            if (tot < 2u) a1 = 0u;
            if (tot < 3u) a2 = 0u;
            lo = ((tot - 1u) << 30) | (a0 & 1023u) | ((a1 & 1023u) << 10) | ((a2 & 1023u) << 20);
        }
        unsigned long long key = ((unsigned long long)__float_as_uint(runmin) << 32) | lo;
        lockey[(size_t)(n0 + rowl) * 8 + cg] = key;
    }
}

// ---------------------------------------------------------------------------
// finish kernel: 1024 blocks x 256 thr, 32 rows/block.
// Per row: prune cgs with local_min > global_min + margin_global (margin uses
// global maxBn — proof: winner's cg always survives). If exactly 1 candidate
// remains (common case) it IS the winner — no recheck. Else bit-exact recheck
// of each candidate / 128-code scan of OVF cgs via exact_key (identical
// arithmetic to R5/R7 — absmax 0.0 preserved, numpy tie rule via key compare).
// Then z_st + one-hot ones + counts + fp64 loss partial (R7 structure).
// ---------------------------------------------------------------------------
__global__ __launch_bounds__(256)
void finish_kernel(const float* __restrict__ z_e,
                   const float* __restrict__ emb,
                   const unsigned long long* __restrict__ lockey,
                   const float* __restrict__ maxbn,
                   uint32_t* __restrict__ counts,
                   double* __restrict__ lp,
                   float* __restrict__ out) {
    __shared__ float zs[32 * 68];
    __shared__ uint32_t scode[32];
    __shared__ double lred[4];
    const int t = threadIdx.x;
    const int n0 = blockIdx.x * 32;                // rows n0..n0+31, same b
    const int b = n0 >> 10, hw0 = n0 & 1023;
    const int hwi = t & 31, dg = t >> 5;           // dg = 0..7
    const size_t base = (size_t)b * 65536 + (size_t)(dg * 8) * 1024 + hw0 + hwi;

    // load z (coalesced 128B per quarter-wave), keep in regs, stage to LDS
    float zreg[8];
#pragma unroll
    for (int k = 0; k < 8; ++k) zreg[k] = z_e[base + (size_t)k * 1024];
#pragma unroll
    for (int m = 0; m < 2; ++m)
        *(float4*)&zs[hwi * 68 + dg * 8 + 4 * m] =
            make_float4(zreg[4 * m], zreg[4 * m + 1], zreg[4 * m + 2], zreg[4 * m + 3]);
    __syncthreads();

    if (t < 32) {
        const unsigned long long* k8 = lockey + (size_t)(n0 + t) * 8;
        unsigned long long kw0 = k8[0], kw1 = k8[1], kw2 = k8[2], kw3 = k8[3];
        unsigned long long kw4 = k8[4], kw5 = k8[5], kw6 = k8[6], kw7 = k8[7];
        unsigned long long kws[8] = {kw0, kw1, kw2, kw3, kw4, kw5, kw6, kw7};
        float gmin = 3.4e38f;
#pragma unroll
        for (int i = 0; i < 8; ++i)
            gmin = fminf(gmin, __uint_as_float((uint32_t)(kws[i] >> 32)));
        const float* xr = &zs[t * 68];
        float A = norm64v((const float4*)xr);
        float mb = maxbn[0];
#pragma unroll
        for (int i = 1; i < 8; ++i) mb = fmaxf(mb, maxbn[i]);
        const float thr = gmin + 0.017f * sqrtf(A * mb) + 1.0e-4f;

        // pass A: survivors count + fast-path single candidate
        int nc = 0; uint32_t first = 0; bool ovf = false;
#pragma unroll
        for (int i = 0; i < 8; ++i) {
            float f = __uint_as_float((uint32_t)(kws[i] >> 32));
            if (f > thr) continue;
            uint32_t lo = (uint32_t)kws[i], cc = lo >> 30;
            if (cc == 3u) ovf = true;
            else { nc += (int)cc + 1; first = lo & 1023u; }
        }
        uint32_t code;
        if (!ovf && nc == 1) {
            code = first;                      // provably the numpy argmin
        } else {
            unsigned long long best = ~0ULL;
#pragma unroll
            for (int i = 0; i < 8; ++i) {
                float f = __uint_as_float((uint32_t)(kws[i] >> 32));
                if (f > thr) continue;
                uint32_t lo = (uint32_t)kws[i], cc = lo >> 30;
                if (cc == 3u) {
#pragma unroll 1
                    for (int c = 0; c < 128; ++c) {
                        unsigned long long key = exact_key(A, xr, emb, (uint32_t)(i * 128 + c));
                        best = (key < best) ? key : best;
                    }
                } else {
#pragma unroll 1
                    for (uint32_t q = 0; q <= cc; ++q) {
                        unsigned long long key = exact_key(A, xr, emb, (lo >> (10u * q)) & 1023u);
                        best = (key < best) ? key : best;
                    }
                }
            }
            code = (uint32_t)best;
        }
        scode[t] = code;
        atomicAdd(&counts[code], 1u);
        out[(size_t)OUT_ENC + (size_t)(n0 + t) * 1024 + code] = 1.0f;
    }
    __syncthreads();

    // z_st + loss from registers (exact per-element math unchanged)
    {
        const uint32_t code = scode[hwi];
        const float4* er4 = (const float4*)(emb + (size_t)code * 64) + dg * 2;
        double ls = 0.0;
#pragma unroll
        for (int k4 = 0; k4 < 2; ++k4) {
            float4 e4 = er4[k4];
            float f0 = e4.x, f1 = e4.y, f2 = e4.z, f3 = e4.w;
            size_t off = base + (size_t)(k4 * 4) * 1024;
            {
                float z = zreg[k4 * 4 + 0]; float tt = f0 - z;
                out[off] = z + tt;              ls += (double)tt * (double)tt;
            }
            {
                float z = zreg[k4 * 4 + 1]; float tt = f1 - z;
                out[off + 1024] = z + tt;       ls += (double)tt * (double)tt;
            }
            {
                float z = zreg[k4 * 4 + 2]; float tt = f2 - z;
                out[off + 2048] = z + tt;       ls += (double)tt * (double)tt;
            }
            {
                float z = zreg[k4 * 4 + 3]; float tt = f3 - z;
                out[off + 3072] = z + tt;       ls += (double)tt * (double)tt;
            }
        }
#pragma unroll
        for (int m = 32; m >= 1; m >>= 1) ls += __shfl_down(ls, m, 64);
        if ((t & 63) == 0) lred[t >> 6] = ls;
    }
    __syncthreads();
    if (t == 0) lp[blockIdx.x] = lred[0] + lred[1] + lred[2] + lred[3];
}

// ---------------------------------------------------------------------------
// scalar kernel: one block; sum 1024 fp64 loss partials + counts entropy.
// Stream ordering (kernel boundary) provides coherence — no fence needed.
// ---------------------------------------------------------------------------
__global__ void scalar_kernel(const uint32_t* __restrict__ counts,
                              const double* __restrict__ lp,
                              float* __restrict__ out) {
    __shared__ double redl[4], redh[4];
    const int t = threadIdx.x;   // 256
    double ls = 0.0;
    for (int i = t; i < 1024; i += 256) ls += lp[i];
    double h = 0.0;
    for (int i = t; i < Kk; i += 256) {
        double p = (double)counts[i] * (1.0 / 32768.0);
        h += p * log(p + 1e-10);
    }
#pragma unroll
    for (int m = 32; m >= 1; m >>= 1) { ls += __shfl_down(ls, m, 64); h += __shfl_down(h, m, 64); }
    if ((t & 63) == 0) { redl[t >> 6] = ls; redh[t >> 6] = h; }
    __syncthreads();
    if (t == 0) {
        double L = redl[0] + redl[1] + redl[2] + redl[3];
        double H = redh[0] + redh[1] + redh[2] + redh[3];
        out[OUT_PERP] = (float)exp(-H);
        float m32 = (float)(L * (1.0 / 2097152.0));
        out[OUT_LOSS] = m32 + 0.25f * m32;   // q + 0.25*e, q==e numerically
    }
}

extern "C" void kernel_launch(void* const* d_in, const int* in_sizes, int n_in,
                              void* d_out, int out_size, void* d_ws, size_t ws_size,
                              hipStream_t stream) {
    const float* z_e = (const float*)d_in[0];
    const float* emb = (const float*)d_in[1];
    float* out = (float*)d_out;
    char* ws = (char*)d_ws;

    uint32_t* counts = (uint32_t*)(ws + WS_CNT);
    double*   lp     = (double*)(ws + WS_LP);
    float*    mbn    = (float*)(ws + WS_MBN);
    unsigned long long* lockey = (unsigned long long*)(ws + WS_KEY);

    // no memsets: counts zeroed by dist block 0; lockey/maxbn/lp fully written
    dist_mfma<<<2048, 256, 0, stream>>>(z_e, emb, lockey, counts, mbn, out);
    finish_kernel<<<1024, 256, 0, stream>>>(z_e, emb, lockey, mbn, counts, lp, out);
    scalar_kernel<<<1, 256, 0, stream>>>(counts, lp, out);
}

// Round 5
// 199.583 us; speedup vs baseline: 1.2252x; 1.2252x over previous
//
#include <hip/hip_runtime.h>
#include <stdint.h>
#include <math.h>

// Problem constants
constexpr int Kk  = 1024;

// d_out layout (floats)
constexpr int OUT0_N   = 32 * 64 * 1024;       // 2097152 (z_st, [B,D,H,W])
constexpr int OUT_LOSS = OUT0_N;               // 2097152
constexpr int OUT_PERP = OUT0_N + 1;           // 2097153
constexpr int OUT_ENC  = OUT0_N + 2;           // 2097154

// d_ws layout (bytes) — everything fully written each call (ws is poisoned):
//   [0      .. 4096)     counts u32[1024]      (zeroed by dist block 0)
//   [4096   .. 12288)    loss partials double[1024] (fully written by finish)
//   [12288  .. 12320)    maxbn float[8]        per-cg max code norm (rg0 blocks)
//   [16384  .. 2113536)  lockey u64[32768][8]  per-(row,cg): {local-min f32 hi,
//                        cnt+3x10bit candidate codes lo} — PLAIN stores, fully
//                        written by dist. No memsets, no contended atomics.
constexpr size_t WS_CNT = 0;
constexpr size_t WS_LP  = 4096;
constexpr size_t WS_MBN = 12288;
constexpr size_t WS_KEY = 16384;

typedef short bf16x8 __attribute__((ext_vector_type(8)));
typedef float f32x16 __attribute__((ext_vector_type(16)));

// ---------------------------------------------------------------------------
// numpy-bit-exact 64-elem squared-norm: tt[d]=fl(x*x), 8 stride-8 sequential
// accumulators, pairwise combine. Contraction OFF. p: 16B-aligned, contiguous.
// ---------------------------------------------------------------------------
__device__ __forceinline__ float norm64v(const float4* __restrict__ p) {
#pragma clang fp contract(off)
    float tt[64];
#pragma unroll
    for (int q = 0; q < 16; ++q) {
        float4 v = p[q];
        tt[4 * q + 0] = v.x * v.x;
        tt[4 * q + 1] = v.y * v.y;
        tt[4 * q + 2] = v.z * v.z;
        tt[4 * q + 3] = v.w * v.w;
    }
    float r[8];
#pragma unroll
    for (int j = 0; j < 8; ++j) r[j] = tt[j];
#pragma unroll
    for (int i = 8; i < 64; i += 8)
#pragma unroll
        for (int j = 0; j < 8; ++j) r[j] += tt[i + j];
    return ((r[0] + r[1]) + (r[2] + r[3])) + ((r[4] + r[5]) + (r[6] + r[7]));
}

__device__ __forceinline__ uint32_t fsort(float f) {
    uint32_t b = __float_as_uint(f);
    return (b & 0x80000000u) ? ~b : (b | 0x80000000u);
}

// RNE float->bf16 (finite inputs only; data is well inside normal range)
__device__ __forceinline__ unsigned short f2bf(float f) {
    uint32_t u = __float_as_uint(f);
    uint32_t r = (u + 0x7fffu + ((u >> 16) & 1u)) >> 16;
    return (unsigned short)r;
}

// exact distance key, bit-identical to the R5/R7 exact kernel:
// C = ascending-d sequential fma chain; A,B via norm64v; dist = fl(fl(A+B)-2C)
// (2C is exact, so fmaf(-2,C,s) == numpy's (A+B) - 2*C elementwise).
__device__ __forceinline__ unsigned long long
exact_key(float A, const float* __restrict__ xr, const float* __restrict__ emb,
          uint32_t code) {
    const float* er = emb + (size_t)code * 64;
    float C = 0.f;
#pragma unroll
    for (int d = 0; d < 64; ++d) C = __builtin_fmaf(xr[d], er[d], C);
    float Bv = norm64v((const float4*)er);
    float s = A + Bv;
    float dist = __builtin_fmaf(-2.f, C, s);
    return ((unsigned long long)fsort(dist) << 32) | code;
}

// ---------------------------------------------------------------------------
// dist_mfma (UNCHANGED from R8 — numerics validated, absmax 0.0):
// 2048 blocks = 256 rowgroups x 8 codegroups, 256 thr, ~34 KB LDS, 4 blk/CU.
// s_hat = Bn_exact - 2*(x.e)_bf16 via mfma_32x32x16_bf16; margin
// 0.017*sqrt(xsq*maxBn)+1e-4 (validated R6/R8). Per-(row,cg) u64:
// {local_min f32, cnt+3x10b candidates | OVF}. 134 MB enc zero-fill rides
// the MFMA tiles.
// ---------------------------------------------------------------------------
__global__ __launch_bounds__(256, 4)
void dist_mfma(const float* __restrict__ z_e, const float* __restrict__ emb,
               unsigned long long* __restrict__ lockey,
               uint32_t* __restrict__ counts,
               float* __restrict__ maxbn,
               float* __restrict__ out) {
    __shared__ unsigned short xbf[128 * 64];   // 16 KB bf16 rows, swizzled
    __shared__ unsigned short ebf[128 * 64];   // 16 KB bf16 codes, swizzled
    __shared__ float Bn_s[128];
    __shared__ float xsqp[2][128];
    __shared__ float mbn_s;
    const int t = threadIdx.x, lane = t & 63, wv = t >> 6, g = lane >> 5;
    const int rg = blockIdx.x >> 3, cg = blockIdx.x & 7;
    const int n0 = rg * 128, b = n0 >> 10, hw0 = n0 & 1023;
    const float* zb = z_e + (size_t)b * 65536 + hw0;

    // ---- x-tile: fp32 global (coalesced d-slices) -> bf16 LDS + xsq partials
    {
        int hwi = t & 127, d4g = t >> 7;
        float xq = 0.f;
#pragma unroll
        for (int it = 0; it < 8; ++it) {
            int dbase = (d4g + it * 2) * 4;
            float v0 = zb[(size_t)(dbase + 0) * 1024 + hwi];
            float v1 = zb[(size_t)(dbase + 1) * 1024 + hwi];
            float v2 = zb[(size_t)(dbase + 2) * 1024 + hwi];
            float v3 = zb[(size_t)(dbase + 3) * 1024 + hwi];
            xq = __builtin_fmaf(v0, v0, xq);
            xq = __builtin_fmaf(v1, v1, xq);
            xq = __builtin_fmaf(v2, v2, xq);
            xq = __builtin_fmaf(v3, v3, xq);
            ushort4 bv;
            bv.x = f2bf(v0); bv.y = f2bf(v1); bv.z = f2bf(v2); bv.w = f2bf(v3);
            *(ushort4*)((char*)xbf + hwi * 128 + ((dbase * 2) ^ ((hwi & 7) << 4))) = bv;
        }
        xsqp[d4g][hwi] = xq;
    }
    // ---- e-tile: contiguous 32 KB fp32 -> bf16 LDS (swizzled) ----
    {
        const float4* ep = (const float4*)(emb + (size_t)cg * 8192);
#pragma unroll
        for (int it = 0; it < 8; ++it) {
            int j = t + it * 256;            // 0..2047
            float4 v = ep[j];
            int code = j >> 4, q = j & 15;
            ushort4 bv;
            bv.x = f2bf(v.x); bv.y = f2bf(v.y); bv.z = f2bf(v.z); bv.w = f2bf(v.w);
            *(ushort4*)((char*)ebf + code * 128 + ((q * 8) ^ ((code & 7) << 4))) = bv;
        }
    }
    // exact code norms from global (L2-hot), numpy-bit-exact
    if (t < 128) Bn_s[t] = norm64v((const float4*)(emb + (size_t)(cg * 128 + t) * 64));
    if (blockIdx.x == 0) ((uint4*)counts)[t] = make_uint4(0u, 0u, 0u, 0u);
    __syncthreads();
    if (wv == 0) {
        float m = fmaxf(Bn_s[lane], Bn_s[lane + 64]);
#pragma unroll
        for (int s = 1; s < 64; s <<= 1) m = fmaxf(m, __shfl_xor(m, s, 64));
        if (lane == 0) { mbn_s = m; if (rg == 0) maxbn[cg] = m; }
    }
    __syncthreads();

    const int rowl = wv * 32 + (lane & 31);
    const float xsq = xsqp[0][rowl] + xsqp[1][rowl];
    const float margin = 0.017f * sqrtf(xsq * mbn_s) + 1.0e-4f;

    const int swz = (lane & 7) << 4;
    bf16x8 bfr[4];
    const char* xb = (const char*)xbf + rowl * 128;
#pragma unroll
    for (int s = 0; s < 4; ++s)
        bfr[s] = *(const bf16x8*)(xb + ((s * 32 + g * 16) ^ swz));
    const char* ebase = (const char*)ebf + (lane & 31) * 128;

    float4* encz = (float4*)(out + OUT_ENC) + (size_t)blockIdx.x * 4096;
    const float4 zero4 = make_float4(0.f, 0.f, 0.f, 0.f);

    // ---- pass 1: row min of s_hat (enc-fill stores ride along) ----
    float runmin = 3.4e38f;
#pragma unroll 1
    for (int tm = 0; tm < 4; ++tm) {
        encz[(size_t)(tm * 2 + 0) * 256 + t] = zero4;
        encz[(size_t)(tm * 2 + 1) * 256 + t] = zero4;
        const char* p = ebase + tm * 4096;
        f32x16 acc = {};
#pragma unroll
        for (int s = 0; s < 4; ++s)
            acc = __builtin_amdgcn_mfma_f32_32x32x16_bf16(
                *(const bf16x8*)(p + ((s * 32 + g * 16) ^ swz)), bfr[s], acc, 0, 0, 0);
#pragma unroll
        for (int r = 0; r < 16; ++r) {
            int cl = tm * 32 + (r & 3) + 8 * (r >> 2) + 4 * g;
            runmin = fminf(runmin, __builtin_fmaf(-2.f, acc[r], Bn_s[cl]));
        }
    }
    runmin = fminf(runmin, __shfl_xor(runmin, 32, 64));   // lane pair = same row
    const float thr = runmin + margin;

    // ---- pass 2: collect candidates (<=3/lane; MFMA recompute, cheap) ----
    uint32_t cnt = 0, c0 = 0, c1 = 0, c2 = 0;
#pragma unroll 1
    for (int tm = 0; tm < 4; ++tm) {
        encz[(size_t)(8 + tm * 2 + 0) * 256 + t] = zero4;
        encz[(size_t)(8 + tm * 2 + 1) * 256 + t] = zero4;
        const char* p = ebase + tm * 4096;
        f32x16 acc = {};
#pragma unroll
        for (int s = 0; s < 4; ++s)
            acc = __builtin_amdgcn_mfma_f32_32x32x16_bf16(
                *(const bf16x8*)(p + ((s * 32 + g * 16) ^ swz)), bfr[s], acc, 0, 0, 0);
#pragma unroll
        for (int r = 0; r < 16; ++r) {
            int cl = tm * 32 + (r & 3) + 8 * (r >> 2) + 4 * g;
            float sv = __builtin_fmaf(-2.f, acc[r], Bn_s[cl]);
            if (sv <= thr) {
                uint32_t gc = (uint32_t)(cg * 128 + cl);
                if (cnt == 0u) c0 = gc; else if (cnt == 1u) c1 = gc; else if (cnt == 2u) c2 = gc;
                ++cnt;
            }
        }
    }
    // merge with partner lane (lane^32: other code-subset of the same row)
    uint32_t pc = __shfl_xor(cnt, 32, 64);
    uint32_t p0 = __shfl_xor(c0, 32, 64);
    uint32_t p1 = __shfl_xor(c1, 32, 64);
    uint32_t p2 = __shfl_xor(c2, 32, 64);
    if (lane < 32) {
        uint32_t tot = cnt + pc;
        uint32_t lo;
        if (tot > 3u || tot == 0u) {
            lo = 3u << 30;                   // OVF -> finish scans this cg
        } else {
            uint32_t a0 = c0, a1 = c1, a2 = c2;
            if (cnt == 0u)      { a0 = p0; a1 = p1; a2 = p2; }
            else if (cnt == 1u) { a1 = p0; a2 = p1; }
            else if (cnt == 2u) { a2 = p0; }
            if (tot < 2u) a1 = 0u;
            if (tot < 3u) a2 = 0u;
            lo = ((tot - 1u) << 30) | (a0 & 1023u) | ((a1 & 1023u) << 10) | ((a2 & 1023u) << 20);
        }
        unsigned long long key = ((unsigned long long)__float_as_uint(runmin) << 32) | lo;
        lockey[(size_t)(n0 + rowl) * 8 + cg] = key;
    }
}

// ---------------------------------------------------------------------------
// finish kernel (R9): 1024 blocks x 256 thr, 32 rows/block.
// R8 post-mortem: rare paths were SERIAL per-lane (an OVF row = 128-code
// dependent-FMA chain on one thread ≈ 30us; kernel = max over blocks). Now:
//  - decode (t<32): survivors via thr = gmin + margin_global; 1-candidate
//    fast path; else enqueue (row,slot,code) pairs / OVF rows in shared
//  - pair rechecks: ONE exact_key PER THREAD across 256 threads (parallel)
//  - OVF rows: block-cooperative 1024-code scan, 4 codes/thread + shfl reduce
// exact_key / norm64v / key+tie rule identical to R5/R7 -> absmax 0.0.
// ---------------------------------------------------------------------------
__global__ __launch_bounds__(256)
void finish_kernel(const float* __restrict__ z_e,
                   const float* __restrict__ emb,
                   const unsigned long long* __restrict__ lockey,
                   const float* __restrict__ maxbn,
                   uint32_t* __restrict__ counts,
                   double* __restrict__ lp,
                   float* __restrict__ out) {
    __shared__ float zs[32 * 68];
    __shared__ float arow[32];                 // exact ||x||^2 per row
    __shared__ uint32_t scode[32];
    __shared__ uint8_t ncarr[32];              // 1=done, 2..6=pairs, 255=OVF
    __shared__ unsigned long long pkey[32][6];
    __shared__ uint32_t pairbuf[192];
    __shared__ uint32_t ovfbuf[32];
    __shared__ uint32_t npairs, novf;
    __shared__ float mbg_s;
    __shared__ unsigned long long rbuf[4];
    __shared__ double lred[4];
    const int t = threadIdx.x, lane = t & 63, wv = t >> 6;
    const int n0 = blockIdx.x * 32;                // rows n0..n0+31, same b
    const int b = n0 >> 10, hw0 = n0 & 1023;
    const int hwi = t & 31, dg = t >> 5;           // dg = 0..7
    const size_t base = (size_t)b * 65536 + (size_t)(dg * 8) * 1024 + hw0 + hwi;

    if (t == 0) {
        npairs = 0u; novf = 0u;
        float mb = maxbn[0];
#pragma unroll
        for (int i = 1; i < 8; ++i) mb = fmaxf(mb, maxbn[i]);
        mbg_s = mb;
    }

    // load z (coalesced 128B per quarter-wave), keep in regs, stage to LDS
    float zreg[8];
#pragma unroll
    for (int k = 0; k < 8; ++k) zreg[k] = z_e[base + (size_t)k * 1024];
#pragma unroll
    for (int m = 0; m < 2; ++m)
        *(float4*)&zs[hwi * 68 + dg * 8 + 4 * m] =
            make_float4(zreg[4 * m], zreg[4 * m + 1], zreg[4 * m + 2], zreg[4 * m + 3]);
    __syncthreads();

    // ---- decode: classify each row ----
    if (t < 32) {
        const unsigned long long* k8 = lockey + (size_t)(n0 + t) * 8;
        unsigned long long kws[8];
#pragma unroll
        for (int i = 0; i < 8; ++i) kws[i] = k8[i];
        float gmin = 3.4e38f;
#pragma unroll
        for (int i = 0; i < 8; ++i)
            gmin = fminf(gmin, __uint_as_float((uint32_t)(kws[i] >> 32)));
        float A = norm64v((const float4*)&zs[t * 68]);
        arow[t] = A;
        const float thr = gmin + 0.017f * sqrtf(A * mbg_s) + 1.0e-4f;

        int nc = 0; uint32_t cand[6]; bool ovf = false;
#pragma unroll
        for (int i = 0; i < 8; ++i) {
            float f = __uint_as_float((uint32_t)(kws[i] >> 32));
            if (f > thr) continue;
            uint32_t lo = (uint32_t)kws[i], cc = lo >> 30;
            if (cc == 3u) { ovf = true; }
            else {
#pragma unroll
                for (uint32_t q = 0; q < 3u; ++q)
                    if (q <= cc) {
                        if (nc < 6) cand[nc] = (lo >> (10u * q)) & 1023u;
                        ++nc;
                    }
            }
        }
        if (ovf || nc > 6 || nc == 0) {
            ncarr[t] = 255u;
            ovfbuf[atomicAdd(&novf, 1u)] = (uint32_t)t;
        } else if (nc == 1) {
            ncarr[t] = 1u;
            scode[t] = cand[0];                // provably the numpy argmin
        } else {
            ncarr[t] = (uint8_t)nc;
            uint32_t bs = atomicAdd(&npairs, (uint32_t)nc);
#pragma unroll
            for (int q = 0; q < 6; ++q)
                if (q < nc)
                    pairbuf[bs + q] = ((uint32_t)t << 13) | ((uint32_t)q << 10) | cand[q];
        }
    }
    __syncthreads();

    // ---- parallel exact rechecks: one (row,code) per thread ----
    for (uint32_t p = t; p < npairs; p += 256u) {
        uint32_t pk = pairbuf[p];
        int row = (int)(pk >> 13), slot = (int)((pk >> 10) & 7u);
        pkey[row][slot] = exact_key(arow[row], &zs[row * 68], emb, pk & 1023u);
    }
    __syncthreads();

    // ---- OVF rows: block-cooperative full 1024-code exact scan ----
    for (uint32_t o = 0; o < novf; ++o) {
        int row = (int)ovfbuf[o];
        const float* xr = &zs[row * 68];
        float A = arow[row];
        unsigned long long best = ~0ULL;
#pragma unroll 1
        for (int cq = 0; cq < 4; ++cq) {
            unsigned long long key = exact_key(A, xr, emb, (uint32_t)(t + cq * 256));
            best = (key < best) ? key : best;
        }
#pragma unroll
        for (int m = 1; m < 64; m <<= 1) {
            unsigned long long ok = __shfl_xor(best, m, 64);
            best = (ok < best) ? ok : best;
        }
        if (lane == 0) rbuf[wv] = best;
        __syncthreads();
        if (t == 0) {
            unsigned long long bb = rbuf[0];
#pragma unroll
            for (int w = 1; w < 4; ++w) bb = (rbuf[w] < bb) ? rbuf[w] : bb;
            scode[row] = (uint32_t)bb;
        }
        __syncthreads();
    }

    // ---- resolve multi-candidate rows ----
    if (t < 32) {
        uint8_t nc = ncarr[t];
        if (nc >= 2u && nc != 255u) {
            unsigned long long bb = pkey[t][0];
#pragma unroll
            for (int q = 1; q < 6; ++q)
                if (q < (int)nc && pkey[t][q] < bb) bb = pkey[t][q];
            scode[t] = (uint32_t)bb;
        }
    }
    __syncthreads();

    if (t < 32) {
        uint32_t code = scode[t];
        atomicAdd(&counts[code], 1u);
        out[(size_t)OUT_ENC + (size_t)(n0 + t) * 1024 + code] = 1.0f;
    }

    // z_st + loss from registers (exact per-element math unchanged)
    {
        const uint32_t code = scode[hwi];
        const float4* er4 = (const float4*)(emb + (size_t)code * 64) + dg * 2;
        double ls = 0.0;
#pragma unroll
        for (int k4 = 0; k4 < 2; ++k4) {
            float4 e4 = er4[k4];
            float f0 = e4.x, f1 = e4.y, f2 = e4.z, f3 = e4.w;
            size_t off = base + (size_t)(k4 * 4) * 1024;
            {
                float z = zreg[k4 * 4 + 0]; float tt = f0 - z;
                out[off] = z + tt;              ls += (double)tt * (double)tt;
            }
            {
                float z = zreg[k4 * 4 + 1]; float tt = f1 - z;
                out[off + 1024] = z + tt;       ls += (double)tt * (double)tt;
            }
            {
                float z = zreg[k4 * 4 + 2]; float tt = f2 - z;
                out[off + 2048] = z + tt;       ls += (double)tt * (double)tt;
            }
            {
                float z = zreg[k4 * 4 + 3]; float tt = f3 - z;
                out[off + 3072] = z + tt;       ls += (double)tt * (double)tt;
            }
        }
#pragma unroll
        for (int m = 32; m >= 1; m >>= 1) ls += __shfl_down(ls, m, 64);
        if ((t & 63) == 0) lred[t >> 6] = ls;
    }
    __syncthreads();
    if (t == 0) lp[blockIdx.x] = lred[0] + lred[1] + lred[2] + lred[3];
}

// ---------------------------------------------------------------------------
// scalar kernel: one block; sum 1024 fp64 loss partials + counts entropy.
// Stream ordering (kernel boundary) provides coherence — no fence needed.
// ---------------------------------------------------------------------------
__global__ void scalar_kernel(const uint32_t* __restrict__ counts,
                              const double* __restrict__ lp,
                              float* __restrict__ out) {
    __shared__ double redl[4], redh[4];
    const int t = threadIdx.x;   // 256
    double ls = 0.0;
    for (int i = t; i < 1024; i += 256) ls += lp[i];
    double h = 0.0;
    for (int i = t; i < Kk; i += 256) {
        double p = (double)counts[i] * (1.0 / 32768.0);
        h += p * log(p + 1e-10);
    }
#pragma unroll
    for (int m = 32; m >= 1; m >>= 1) { ls += __shfl_down(ls, m, 64); h += __shfl_down(h, m, 64); }
    if ((t & 63) == 0) { redl[t >> 6] = ls; redh[t >> 6] = h; }
    __syncthreads();
    if (t == 0) {
        double L = redl[0] + redl[1] + redl[2] + redl[3];
        double H = redh[0] + redh[1] + redh[2] + redh[3];
        out[OUT_PERP] = (float)exp(-H);
        float m32 = (float)(L * (1.0 / 2097152.0));
        out[OUT_LOSS] = m32 + 0.25f * m32;   // q + 0.25*e, q==e numerically
    }
}

extern "C" void kernel_launch(void* const* d_in, const int* in_sizes, int n_in,
                              void* d_out, int out_size, void* d_ws, size_t ws_size,
                              hipStream_t stream) {
    const float* z_e = (const float*)d_in[0];
    const float* emb = (const float*)d_in[1];
    float* out = (float*)d_out;
    char* ws = (char*)d_ws;

    uint32_t* counts = (uint32_t*)(ws + WS_CNT);
    double*   lp     = (double*)(ws + WS_LP);
    float*    mbn    = (float*)(ws + WS_MBN);
    unsigned long long* lockey = (unsigned long long*)(ws + WS_KEY);

    // no memsets: counts zeroed by dist block 0; lockey/maxbn/lp fully written
    dist_mfma<<<2048, 256, 0, stream>>>(z_e, emb, lockey, counts, mbn, out);
    finish_kernel<<<1024, 256, 0, stream>>>(z_e, emb, lockey, mbn, counts, lp, out);
    scalar_kernel<<<1, 256, 0, stream>>>(counts, lp, out);
}